// Round 1
// baseline (1349.183 us; speedup 1.0000x reference)
//
#include <hip/hip_runtime.h>
#include <stdint.h>

#define B_  4
#define EH_ 512
#define T_  256
#define PH_ 320
#define U_  128
#define JH_ 512
#define NC_ 1025

typedef __attribute__((ext_vector_type(8))) short short8;
typedef __attribute__((ext_vector_type(4))) float floatx4;

__device__ __forceinline__ unsigned short f2bf(float f) {
    unsigned int x = __float_as_uint(f);
    x += 0x7fffu + ((x >> 16) & 1u);
    return (unsigned short)(x >> 16);
}
__device__ __forceinline__ float bf2f(unsigned short u) {
    return __uint_as_float(((unsigned int)u) << 16);
}

// ---------------- P1: e = enc^T @ W_enc + b_enc  -> [B*T, JH] fp32 -----------
__global__ __launch_bounds__(512) void enc_proj(const float* __restrict__ enc,
                                                const float* __restrict__ W_enc,
                                                const float* __restrict__ b_enc,
                                                float* __restrict__ e_out) {
    __shared__ float a_lds[8][EH_];
    const int tid = threadIdx.x;
    const int mb = blockIdx.x * 8;   // rows m = b*T + t ; 8 consecutive t, same b
    const int b  = mb >> 8;          // /T_
    const int t0 = mb & (T_ - 1);
    {
        // thread tid loads k=tid for the 8 rows: enc[b][tid][t0..t0+7] contiguous
        const float* src = enc + ((size_t)(b * EH_ + tid) * T_ + t0);
        float4 v0 = *(const float4*)(src);
        float4 v1 = *(const float4*)(src + 4);
        a_lds[0][tid] = v0.x; a_lds[1][tid] = v0.y; a_lds[2][tid] = v0.z; a_lds[3][tid] = v0.w;
        a_lds[4][tid] = v1.x; a_lds[5][tid] = v1.y; a_lds[6][tid] = v1.z; a_lds[7][tid] = v1.w;
    }
    __syncthreads();
    float acc[8];
    const float bias = b_enc[tid];
#pragma unroll
    for (int i = 0; i < 8; i++) acc[i] = bias;
    for (int k4 = 0; k4 < EH_ / 4; k4++) {
        const float w0 = W_enc[(k4 * 4 + 0) * JH_ + tid];
        const float w1 = W_enc[(k4 * 4 + 1) * JH_ + tid];
        const float w2 = W_enc[(k4 * 4 + 2) * JH_ + tid];
        const float w3 = W_enc[(k4 * 4 + 3) * JH_ + tid];
#pragma unroll
        for (int i = 0; i < 8; i++) {
            float4 a = *(const float4*)(&a_lds[i][k4 * 4]);
            acc[i] = fmaf(a.x, w0, acc[i]);
            acc[i] = fmaf(a.y, w1, acc[i]);
            acc[i] = fmaf(a.z, w2, acc[i]);
            acc[i] = fmaf(a.w, w3, acc[i]);
        }
    }
#pragma unroll
    for (int i = 0; i < 8; i++) e_out[(mb + i) * JH_ + tid] = acc[i];
}

// ---------------- P2: p = dec^T @ W_pred + b_pred -> [B*U, JH] fp32 ----------
__global__ __launch_bounds__(512) void pred_proj(const float* __restrict__ dec,
                                                 const float* __restrict__ W_pred,
                                                 const float* __restrict__ b_pred,
                                                 float* __restrict__ p_out) {
    __shared__ float a_lds[8][PH_];
    const int tid = threadIdx.x;
    const int mb = blockIdx.x * 8;   // rows m = b*U + u
    const int b  = mb >> 7;          // /U_
    const int u0 = mb & (U_ - 1);
    if (tid < PH_) {
        const float* src = dec + ((size_t)(b * PH_ + tid) * U_ + u0);
        float4 v0 = *(const float4*)(src);
        float4 v1 = *(const float4*)(src + 4);
        a_lds[0][tid] = v0.x; a_lds[1][tid] = v0.y; a_lds[2][tid] = v0.z; a_lds[3][tid] = v0.w;
        a_lds[4][tid] = v1.x; a_lds[5][tid] = v1.y; a_lds[6][tid] = v1.z; a_lds[7][tid] = v1.w;
    }
    __syncthreads();
    float acc[8];
    const float bias = b_pred[tid];
#pragma unroll
    for (int i = 0; i < 8; i++) acc[i] = bias;
    for (int k4 = 0; k4 < PH_ / 4; k4++) {
        const float w0 = W_pred[(k4 * 4 + 0) * JH_ + tid];
        const float w1 = W_pred[(k4 * 4 + 1) * JH_ + tid];
        const float w2 = W_pred[(k4 * 4 + 2) * JH_ + tid];
        const float w3 = W_pred[(k4 * 4 + 3) * JH_ + tid];
#pragma unroll
        for (int i = 0; i < 8; i++) {
            float4 a = *(const float4*)(&a_lds[i][k4 * 4]);
            acc[i] = fmaf(a.x, w0, acc[i]);
            acc[i] = fmaf(a.y, w1, acc[i]);
            acc[i] = fmaf(a.z, w2, acc[i]);
            acc[i] = fmaf(a.w, w3, acc[i]);
        }
    }
#pragma unroll
    for (int i = 0; i < 8; i++) p_out[(mb + i) * JH_ + tid] = acc[i];
}

// ---------------- P3: W_T[c][k] = bf16(W_out[k][c]), c in [0,1025) ----------
__global__ __launch_bounds__(256) void wt_prep(const float* __restrict__ W_out,
                                               unsigned short* __restrict__ WT) {
    __shared__ float tile[64][65];
    const int tid = threadIdx.x;
    const int c0 = (blockIdx.x % 17) * 64;
    const int k0 = (blockIdx.x / 17) * 64;
#pragma unroll
    for (int p = 0; p < 16; p++) {
        int ki = p * 4 + (tid >> 6);
        int ci = tid & 63;
        int c = c0 + ci;
        tile[ki][ci] = (c < NC_) ? W_out[(k0 + ki) * NC_ + c] : 0.0f;
    }
    __syncthreads();
#pragma unroll
    for (int p = 0; p < 16; p++) {
        int ci = p * 4 + (tid >> 6);
        int ki = tid & 63;
        int c = c0 + ci;
        if (c < NC_) WT[c * JH_ + (k0 + ki)] = f2bf(tile[ki][ci]);
    }
}

// ---------------- Main fused joint: logits + log_softmax, single pass --------
// grid = (B*T*U)/64 = 2048 blocks, 512 threads (8 waves).
// Block: 64 rows (one (b,t), u0..u0+63) x full N. Wave w: columns [w*128, w*128+128).
__global__ __launch_bounds__(512, 2) void joint_kernel(
        const float* __restrict__ e, const float* __restrict__ p,
        const unsigned short* __restrict__ WT,
        const float* __restrict__ b_out, float* __restrict__ out) {
    __shared__ unsigned short h_lds[64 * 256];  // half-K tile, XOR-swizzled 16B chunks
    __shared__ float stripes[8][64];
    __shared__ float rowmax_lds[64];
    __shared__ float lse_lds[64];
    __shared__ float c1024_lds[64];

    const int tid = threadIdx.x;
    const int m0 = blockIdx.x * 64;
    const int bb = m0 >> 15;             // /(T*U)
    const int tt = (m0 >> 7) & (T_ - 1);
    const int u0 = m0 & (U_ - 1);        // 0 or 64

    const int wave = tid >> 6;
    const int lane = tid & 63;
    const int qd = lane >> 4;
    const int ln = lane & 15;
    const int n0 = wave << 7;

    floatx4 acc[4][8];
#pragma unroll
    for (int i = 0; i < 4; i++)
#pragma unroll
        for (int nt = 0; nt < 8; nt++) acc[i][nt] = (floatx4){0.f, 0.f, 0.f, 0.f};

    const int kk = tid & 255;
    const int rpar = tid >> 8;
    const float* e_row = e + (size_t)(bb * T_ + tt) * JH_;
    const float* p_base = p + (size_t)(bb * U_ + u0) * JH_;

    float c1024_part = 0.0f;
    const int rr = tid >> 3;   // row for col-1024 dot (8 threads/row)
    const int g  = tid & 7;

    for (int ph = 0; ph < 2; ph++) {
        const int kbase = ph * 256;
        // ---- stage h = relu(e + p) as bf16, swizzled ----
        const float ev = e_row[kbase + kk];
        for (int r0 = 0; r0 < 64; r0 += 2) {
            int r = r0 + rpar;
            float hv = ev + p_base[r * JH_ + kbase + kk];
            hv = hv > 0.f ? hv : 0.f;
            int pc = (kk >> 3) ^ (r & 7);
            h_lds[r * 256 + pc * 8 + (kk & 7)] = f2bf(hv);
        }
        __syncthreads();
        // ---- K loop: 8 steps of 32 ----
        for (int ks = 0; ks < 8; ks++) {
            const int k0l = ks * 32;
            short8 a[4];
#pragma unroll
            for (int i = 0; i < 4; i++) {
                int m = i * 16 + ln;
                int pc = ((k0l >> 3) + qd) ^ (m & 7);
                a[i] = *(const short8*)(&h_lds[m * 256 + pc * 8]);
            }
#pragma unroll
            for (int nt = 0; nt < 8; nt++) {
                const short8 bfrag = *(const short8*)(WT +
                        ((n0 + nt * 16 + ln) * JH_ + kbase + k0l + qd * 8));
#pragma unroll
                for (int i = 0; i < 4; i++)
                    acc[i][nt] = __builtin_amdgcn_mfma_f32_16x16x32_bf16(
                            a[i], bfrag, acc[i][nt], 0, 0, 0);
            }
        }
        // ---- column 1024 partial dot (VALU) ----
#pragma unroll
        for (int cc = 0; cc < 4; cc++) {
            int c = g * 4 + cc;
            int pc = c ^ (rr & 7);
#pragma unroll
            for (int o = 0; o < 8; o++) {
                c1024_part += bf2f(h_lds[rr * 256 + pc * 8 + o]) *
                              bf2f(WT[1024 * JH_ + kbase + c * 8 + o]);
            }
        }
        __syncthreads();   // before next-phase restage overwrites h_lds
    }

    // reduce col-1024 over the 8 threads of each row
    c1024_part += __shfl_down(c1024_part, 4, 8);
    c1024_part += __shfl_down(c1024_part, 2, 8);
    c1024_part += __shfl_down(c1024_part, 1, 8);

    // ---- bias add ----
#pragma unroll
    for (int nt = 0; nt < 8; nt++) {
        float bv = b_out[n0 + nt * 16 + ln];
#pragma unroll
        for (int i = 0; i < 4; i++) {
            acc[i][nt][0] += bv; acc[i][nt][1] += bv;
            acc[i][nt][2] += bv; acc[i][nt][3] += bv;
        }
    }

    // ---- row max (per lane over nt, then width-16 shuffle across columns) ----
    float mx[4][4];
#pragma unroll
    for (int i = 0; i < 4; i++)
#pragma unroll
        for (int r = 0; r < 4; r++) {
            float m = acc[i][0][r];
#pragma unroll
            for (int nt = 1; nt < 8; nt++) m = fmaxf(m, acc[i][nt][r]);
            m = fmaxf(m, __shfl_xor(m, 1, 16));
            m = fmaxf(m, __shfl_xor(m, 2, 16));
            m = fmaxf(m, __shfl_xor(m, 4, 16));
            m = fmaxf(m, __shfl_xor(m, 8, 16));
            mx[i][r] = m;
        }
    if (ln == 0) {
#pragma unroll
        for (int i = 0; i < 4; i++)
#pragma unroll
            for (int r = 0; r < 4; r++)
                stripes[wave][i * 16 + qd * 4 + r] = mx[i][r];
    }
    if (g == 0) c1024_lds[rr] = c1024_part + b_out[NC_ - 1];
    __syncthreads();
    if (tid < 64) {
        float m = c1024_lds[tid];
#pragma unroll
        for (int w = 0; w < 8; w++) m = fmaxf(m, stripes[w][tid]);
        rowmax_lds[tid] = m;
    }
    __syncthreads();

    // ---- sum of exp ----
#pragma unroll
    for (int i = 0; i < 4; i++)
#pragma unroll
        for (int r = 0; r < 4; r++) {
            float rm = rowmax_lds[i * 16 + qd * 4 + r];
            float s = 0.f;
#pragma unroll
            for (int nt = 0; nt < 8; nt++) s += __expf(acc[i][nt][r] - rm);
            s += __shfl_xor(s, 1, 16);
            s += __shfl_xor(s, 2, 16);
            s += __shfl_xor(s, 4, 16);
            s += __shfl_xor(s, 8, 16);
            mx[i][r] = s;  // reuse storage for stripe sums
        }
    if (ln == 0) {
#pragma unroll
        for (int i = 0; i < 4; i++)
#pragma unroll
            for (int r = 0; r < 4; r++)
                stripes[wave][i * 16 + qd * 4 + r] = mx[i][r];
    }
    __syncthreads();
    if (tid < 64) {
        float rm = rowmax_lds[tid];
        float s = __expf(c1024_lds[tid] - rm);
#pragma unroll
        for (int w = 0; w < 8; w++) s += stripes[w][tid];
        float l = rm + __logf(s);
        lse_lds[tid] = l;
        out[(size_t)(m0 + tid) * NC_ + (NC_ - 1)] = c1024_lds[tid] - l;
    }
    __syncthreads();

    // ---- write normalized logits ----
#pragma unroll
    for (int i = 0; i < 4; i++)
#pragma unroll
        for (int r = 0; r < 4; r++) {
            int row = i * 16 + qd * 4 + r;
            float l = lse_lds[row];
            float* dst = out + (size_t)(m0 + row) * NC_ + n0 + ln;
#pragma unroll
            for (int nt = 0; nt < 8; nt++) dst[nt * 16] = acc[i][nt][r] - l;
        }
}

extern "C" void kernel_launch(void* const* d_in, const int* in_sizes, int n_in,
                              void* d_out, int out_size, void* d_ws, size_t ws_size,
                              hipStream_t stream) {
    const float* enc    = (const float*)d_in[0];
    const float* dec    = (const float*)d_in[1];
    const float* W_enc  = (const float*)d_in[2];
    const float* b_enc  = (const float*)d_in[3];
    const float* W_pred = (const float*)d_in[4];
    const float* b_pred = (const float*)d_in[5];
    const float* W_out  = (const float*)d_in[6];
    const float* b_out  = (const float*)d_in[7];
    float* out = (float*)d_out;

    char* ws = (char*)d_ws;
    float* e_buf = (float*)ws;                                // 2 MiB: [1024][512] f32
    float* p_buf = (float*)(ws + (2u << 20));                 // 1 MiB: [512][512] f32
    unsigned short* WT = (unsigned short*)(ws + (3u << 20));  // ~1 MiB: [1025][512] bf16

    enc_proj<<<dim3(128), dim3(512), 0, stream>>>(enc, W_enc, b_enc, e_buf);
    pred_proj<<<dim3(64), dim3(512), 0, stream>>>(dec, W_pred, b_pred, p_buf);
    wt_prep<<<dim3(17 * 8), dim3(256), 0, stream>>>(W_out, WT);
    joint_kernel<<<dim3(2048), dim3(512), 0, stream>>>(e_buf, p_buf, WT, b_out, out);
}